// Round 6
// baseline (340.068 us; speedup 1.0000x reference)
//
#include <hip/hip_runtime.h>
#include <hip/hip_bf16.h>
#include <cstddef>

// ILA_10986526343542: linear attention block, bf16-MFMA pipeline.
// x:[8,256,128,128] fp32. Math:
//   ek  = exp(s*(Wk@x+bk)) bf16 [b][c][n]      (proj_mfma)
//   T   = ek @ x^T (8 n-chunks) + row-sum partials (t_mfma -> Tpart, ksump)
//   Tred= (sum_chunks T)/ksum  (in-place ch.0)  (treduce)
//   ctx = Tred@Wv^T + bv                        (ctx_pass)
//   M   = Wo_h @ ctx_h^T  (bf16)                (mpass)
//   eq  = exp(s*(Wq@x+bq)) bf16 [b][c][n]      (proj_mfma, reuses ek buffer)
//   invZ[b,n,h] = 1/sum_{c in head} eq[c][n]    (invz_pass)
//   out = M @ (eq^T * invZ) + bo                (out_mfma)

constexpr int   NPIX     = 16384;
constexpr float QK_SCALE = 0.42044820762685725f;  // 32^-0.25

typedef __attribute__((ext_vector_type(8))) short          bf16x8;
typedef __attribute__((ext_vector_type(8))) unsigned short u16x8;
typedef __attribute__((ext_vector_type(4))) float          f32x4;

__device__ __forceinline__ float bf2f(unsigned short v) {
    union { unsigned int u; float f; } c; c.u = ((unsigned int)v) << 16; return c.f;
}
__device__ __forceinline__ unsigned short f2bf(float f) {
    union { __hip_bfloat16 h; unsigned short s; } c; c.h = __float2bfloat16(f); return c.s;
}

// ---- 0: weights to bf16 ----------------------------------------------------
__global__ __launch_bounds__(256) void prep(
    const float* __restrict__ Wq, const float* __restrict__ Wk,
    unsigned short* __restrict__ Wqb, unsigned short* __restrict__ Wkb)
{
    const int i = blockIdx.x * 256 + threadIdx.x;   // 65536 total
    Wqb[i] = f2bf(Wq[i]);
    Wkb[i] = f2bf(Wk[i]);
}

// ---- 1/6: projection via MFMA ---------------------------------------------
// A-fragments direct from global (bf16 W, L2-resident). B staged through a
// 10 KB transposed LDS tile. Direct scalar stores of exp() as [c][n].
__global__ __launch_bounds__(256) void proj_mfma(
    const float* __restrict__ x, const unsigned short* __restrict__ Wb,
    const float* __restrict__ bias, unsigned short* __restrict__ eout)
{
    __shared__ unsigned short BsT[128][40];   // [pixel][k], 10240 B
    const int b  = blockIdx.z;
    const int m0 = blockIdx.y * 128;
    const int n0 = blockIdx.x * 128;
    const int t  = threadIdx.x;
    const int w  = t >> 6, l = t & 63;
    const int lm = l & 15, lg = l >> 4;
    const int mwl = (w & 1) * 64;          // wave m offset within tile
    const int nwl = (w >> 1) * 64;         // wave n offset within tile

    const float* xb = x + (size_t)b * 256 * NPIX + n0;
    const unsigned short* arow = Wb + (size_t)(m0 + mwl) * 256;

    const int np = (t & 63) * 2, kq = (t >> 6) * 8;   // B-stage mapping

    f32x4 acc[4][4] = {};
    for (int k0 = 0; k0 < 256; k0 += 32) {
        {   // stage B: x columns -> transposed LDS tile BsT[n][k]
            const float* src = xb + (size_t)(k0 + kq) * NPIX + np;
            float2 v[8];
            #pragma unroll
            for (int r = 0; r < 8; ++r)
                v[r] = *(const float2*)(src + (size_t)r * NPIX);
            u16x8 pa, pb;
            #pragma unroll
            for (int r = 0; r < 8; ++r) { pa[r] = f2bf(v[r].x); pb[r] = f2bf(v[r].y); }
            *(u16x8*)&BsT[np][kq]     = pa;
            *(u16x8*)&BsT[np + 1][kq] = pb;
        }
        __syncthreads();
        bf16x8 afr[4], bfr[4];
        #pragma unroll
        for (int i = 0; i < 4; ++i)
            afr[i] = *(const bf16x8*)(arow + (size_t)(i*16 + lm) * 256 + k0 + lg*8);
        #pragma unroll
        for (int j = 0; j < 4; ++j) bfr[j] = *(const bf16x8*)&BsT[nwl + j*16 + lm][lg*8];
        #pragma unroll
        for (int i = 0; i < 4; ++i)
            #pragma unroll
            for (int j = 0; j < 4; ++j)
                acc[i][j] = __builtin_amdgcn_mfma_f32_16x16x32_bf16(afr[i], bfr[j], acc[i][j], 0, 0, 0);
        __syncthreads();
    }

    // epilogue: exp + bf16, direct scalar stores (L2 write-combines)
    const int mw = m0 + mwl, nw = n0 + nwl;
    #pragma unroll
    for (int i = 0; i < 4; ++i) {
        const f32x4 bb4 = *(const f32x4*)(bias + mw + i*16 + lg*4);
        #pragma unroll
        for (int r = 0; r < 4; ++r) {
            const int gm = mw + i*16 + lg*4 + r;
            unsigned short* dst = eout + ((size_t)b*256 + gm) * NPIX + nw;
            #pragma unroll
            for (int j = 0; j < 4; ++j)
                dst[j*16 + lm] = f2bf(__expf(QK_SCALE * (acc[i][j][r] + bb4[r])));
        }
    }
}

// ---- 2: Tpart[b][chunk] = ek @ x^T via MFMA + ksum partials ----------------
__global__ __launch_bounds__(256) void t_mfma(
    const unsigned short* __restrict__ ek, const float* __restrict__ x,
    float* __restrict__ Tpart, float* __restrict__ ksump)
{
    __shared__ unsigned short As[128][40];
    __shared__ unsigned short Bs[128][40];
    const int quad  = blockIdx.x;        // 0..3 -> (m-tile, c-tile)
    const int chunk = blockIdx.y;        // 0..7
    const int b     = blockIdx.z;
    const int mt = (quad >> 1) * 128;    // key-channel tile
    const int ct = (quad & 1) * 128;     // channel tile
    const bool do_ks = (quad & 1) == 0;  // row-sums once per (b,chunk,mt)
    const int t  = threadIdx.x;
    const int w  = t >> 6, l = t & 63;
    const int lm = l & 15, lg = l >> 4;
    const int mw = (w & 1) * 64, cw = (w >> 1) * 64;
    const int sr = t >> 1, sh = (t & 1) * 16;

    const unsigned short* ekb = ek + ((size_t)b*256 + mt) * NPIX;
    const float*          xb  = x  + ((size_t)b*256 + ct) * NPIX;

    f32x4 acc[4][4] = {};
    float krow = 0.f;
    const int p0base = chunk * 2048;
    for (int p0 = p0base; p0 < p0base + 2048; p0 += 32) {
        {   // stage A: ek rows (bf16 direct) + row-sum accumulation
            const unsigned short* src = ekb + (size_t)sr * NPIX + p0 + sh;
            u16x8 a0 = *(const u16x8*)src;
            u16x8 a1 = *(const u16x8*)(src + 8);
            *(u16x8*)&As[sr][sh]     = a0;
            *(u16x8*)&As[sr][sh + 8] = a1;
            if (do_ks) {
                #pragma unroll
                for (int u = 0; u < 8; ++u) krow += bf2f(a0[u]) + bf2f(a1[u]);
            }
        }
        {   // stage B: x rows (fp32 -> bf16)
            const float* src = xb + (size_t)sr * NPIX + p0 + sh;
            u16x8 a, c;
            #pragma unroll
            for (int u = 0; u < 8; ++u) { a[u] = f2bf(src[u]); c[u] = f2bf(src[8+u]); }
            *(u16x8*)&Bs[sr][sh]     = a;
            *(u16x8*)&Bs[sr][sh + 8] = c;
        }
        __syncthreads();
        bf16x8 afr[4], bfr[4];
        #pragma unroll
        for (int i = 0; i < 4; ++i) afr[i] = *(const bf16x8*)&As[mw + i*16 + lm][lg*8];
        #pragma unroll
        for (int j = 0; j < 4; ++j) bfr[j] = *(const bf16x8*)&Bs[cw + j*16 + lm][lg*8];
        #pragma unroll
        for (int i = 0; i < 4; ++i)
            #pragma unroll
            for (int j = 0; j < 4; ++j)
                acc[i][j] = __builtin_amdgcn_mfma_f32_16x16x32_bf16(afr[i], bfr[j], acc[i][j], 0, 0, 0);
        __syncthreads();
    }

    if (do_ks) {   // pair (t, t^1) holds the two 16-px halves of row sr
        krow += __shfl_xor(krow, 1, 64);
        if ((t & 1) == 0)
            ksump[((size_t)b*8 + chunk)*256 + mt + sr] = krow;
    }

    float* dst = Tpart + (((size_t)b*8 + chunk) * 256) * 256;
    #pragma unroll
    for (int i = 0; i < 4; ++i)
        #pragma unroll
        for (int r = 0; r < 4; ++r) {
            const int gm = mt + mw + i*16 + lg*4 + r;
            #pragma unroll
            for (int j = 0; j < 4; ++j)
                dst[(size_t)gm * 256 + ct + cw + j*16 + lm] = acc[i][j][r];
        }
}

// ---- 3a: reduce Tpart chunks in place (chunk 0 slot), fold 1/ksum ----------
__global__ __launch_bounds__(256) void treduce(
    float* __restrict__ Tpart, const float* __restrict__ ksump)
{
    const int gid = blockIdx.x * 256 + threadIdx.x;   // 0..131071 (x4 floats)
    const int b   = gid >> 14;
    const int rem = gid & 16383;
    const int r   = rem >> 6;
    const int c4  = (rem & 63) * 4;
    float ks = 0.f;
    #pragma unroll
    for (int ch = 0; ch < 8; ++ch) ks += ksump[((size_t)b*8 + ch)*256 + r];
    float* base = Tpart + (((size_t)b*8) * 256 + r) * 256 + c4;   // chunk 0
    f32x4 s = *(f32x4*)base;
    #pragma unroll
    for (int ch = 1; ch < 8; ++ch) {
        f32x4 v = *(const f32x4*)(base + (size_t)ch * 65536);
        s.x += v.x; s.y += v.y; s.z += v.z; s.w += v.w;
    }
    const float inv = 1.0f / ks;
    s.x *= inv; s.y *= inv; s.z *= inv; s.w *= inv;
    *(f32x4*)base = s;   // each thread owns its address: race-free
}

// ---- 3b: ctx[b][h][d][e] = Tred[b][h*32+d,:]·Wv[h*64+e,:] + bv[h*64+e] ----
__global__ __launch_bounds__(256) void ctx_pass(
    const float* __restrict__ Tpart, const float* __restrict__ Wv,
    const float* __restrict__ bv, float* __restrict__ ctx)
{
    const int gid = blockIdx.x * 256 + threadIdx.x;   // 0..131071
    const int b   = gid >> 14;
    const int rem = gid & 16383;
    const int h   = rem >> 11;
    const int de  = rem & 2047;
    const int d   = de >> 6;
    const int e   = de & 63;
    const float* tp = Tpart + (((size_t)b*8) * 256 + h*32 + d) * 256;  // Tred row
    const float* wv = Wv + (size_t)(h*64 + e) * 256;
    float sx = 0.f, sy = 0.f, sz = 0.f, sw = 0.f;
    #pragma unroll 8
    for (int c = 0; c < 256; c += 4) {
        f32x4 a = *(const f32x4*)(tp + c);
        f32x4 w = *(const f32x4*)(wv + c);
        sx = fmaf(a.x, w.x, sx); sy = fmaf(a.y, w.y, sy);
        sz = fmaf(a.z, w.z, sz); sw = fmaf(a.w, w.w, sw);
    }
    ctx[gid] = (sx + sy) + (sz + sw) + bv[h*64 + e];
}

// ---- 3c: M[b][o][h*32+d] = sum_e Wo[o][h*64+e]*ctx[b][h][d][e] (bf16) ------
__global__ __launch_bounds__(256) void mpass(
    const float* __restrict__ ctx, const float* __restrict__ Wo,
    unsigned short* __restrict__ Mb)
{
    const int gid = blockIdx.x * 256 + threadIdx.x;   // 0..524287
    const int b   = gid >> 16;
    const int rem = gid & 65535;
    const int o   = rem >> 8;
    const int dg  = rem & 255;
    const int h   = dg >> 5;
    const int d   = dg & 31;
    const float* cp = ctx + ((size_t)b*8 + h) * 2048 + d*64;
    const float* wp = Wo + (size_t)o * 512 + h*64;
    float sx = 0.f, sy = 0.f, sz = 0.f, sw = 0.f;
    #pragma unroll
    for (int e = 0; e < 64; e += 4) {
        f32x4 a = *(const f32x4*)(cp + e);
        f32x4 w = *(const f32x4*)(wp + e);
        sx = fmaf(a.x, w.x, sx); sy = fmaf(a.y, w.y, sy);
        sz = fmaf(a.z, w.z, sz); sw = fmaf(a.w, w.w, sw);
    }
    Mb[((size_t)b*256 + o) * 256 + dg] = f2bf((sx + sy) + (sz + sw));
}

// ---- 7: invZ[b][n][h] = 1 / sum_{c in head h} eq[c][n] ---------------------
__global__ __launch_bounds__(256) void invz_pass(
    const unsigned short* __restrict__ eq, float* __restrict__ invZ)
{
    const int b = blockIdx.y;
    const int n = blockIdx.x * 256 + threadIdx.x;
    const unsigned short* base = eq + (size_t)b * 256 * NPIX + n;
    float* o = invZ + ((size_t)b * NPIX + n) * 8;
    #pragma unroll
    for (int h = 0; h < 8; ++h) {
        float s = 0.f;
        #pragma unroll
        for (int d = 0; d < 32; ++d)
            s += bf2f(base[(size_t)(h*32 + d) * NPIX]);
        o[h] = 1.0f / s;
    }
}

// ---- 8: out = M[b] @ (eq^T * invZ) + bo via MFMA ---------------------------
__global__ __launch_bounds__(256) void out_mfma(
    const unsigned short* __restrict__ eq, const float* __restrict__ invZ,
    const unsigned short* __restrict__ Mb, const float* __restrict__ bo,
    float* __restrict__ out)
{
    __shared__ unsigned short BsT[128][40];   // [pixel][k]
    const int b  = blockIdx.z;
    const int m0 = blockIdx.y * 128;
    const int n0 = blockIdx.x * 128;
    const int t  = threadIdx.x;
    const int w  = t >> 6, l = t & 63;
    const int lm = l & 15, lg = l >> 4;
    const int mw = (w & 1) * 64, nw = (w >> 1) * 64;
    const int np = (t & 63) * 2, kq = (t >> 6) * 8;

    const unsigned short* Ab  = Mb + ((size_t)b*256 + m0 + mw) * 256;
    const unsigned short* Bb  = eq + (size_t)b * 256 * NPIX + n0;
    const float*          izb = invZ + ((size_t)b * NPIX + n0) * 8;

    f32x4 acc[4][4] = {};
    for (int k0 = 0; k0 < 256; k0 += 32) {
        const int h = k0 >> 5;   // K-step spans exactly one head
        {   // stage B: eq columns * invZ -> transposed LDS tile
            const unsigned short* src = Bb + (size_t)(k0 + kq) * NPIX + np;
            const float iz0 = izb[(size_t)np * 8 + h];
            const float iz1 = izb[(size_t)(np + 1) * 8 + h];
            ushort2 v[8];
            #pragma unroll
            for (int r = 0; r < 8; ++r)
                v[r] = *(const ushort2*)(src + (size_t)r * NPIX);
            u16x8 pa, pb;
            #pragma unroll
            for (int r = 0; r < 8; ++r) {
                pa[r] = f2bf(bf2f(v[r].x) * iz0);
                pb[r] = f2bf(bf2f(v[r].y) * iz1);
            }
            *(u16x8*)&BsT[np][kq]     = pa;
            *(u16x8*)&BsT[np + 1][kq] = pb;
        }
        __syncthreads();
        bf16x8 afr[4], bfr[4];
        #pragma unroll
        for (int i = 0; i < 4; ++i)
            afr[i] = *(const bf16x8*)(Ab + (size_t)(i*16 + lm) * 256 + k0 + lg*8);
        #pragma unroll
        for (int j = 0; j < 4; ++j) bfr[j] = *(const bf16x8*)&BsT[nw + j*16 + lm][lg*8];
        #pragma unroll
        for (int i = 0; i < 4; ++i)
            #pragma unroll
            for (int j = 0; j < 4; ++j)
                acc[i][j] = __builtin_amdgcn_mfma_f32_16x16x32_bf16(afr[i], bfr[j], acc[i][j], 0, 0, 0);
        __syncthreads();
    }

    #pragma unroll
    for (int i = 0; i < 4; ++i) {
        const f32x4 bb4 = *(const f32x4*)(bo + m0 + mw + i*16 + lg*4);
        #pragma unroll
        for (int r = 0; r < 4; ++r) {
            const int gm = m0 + mw + i*16 + lg*4 + r;
            float* dst = out + ((size_t)b*256 + gm) * NPIX + n0 + nw;
            #pragma unroll
            for (int j = 0; j < 4; ++j)
                dst[j*16 + lm] = acc[i][j][r] + bb4[r];
        }
    }
}

// ---------------------------------------------------------------------------
extern "C" void kernel_launch(void* const* d_in, const int* in_sizes, int n_in,
                              void* d_out, int out_size, void* d_ws, size_t ws_size,
                              hipStream_t stream)
{
    const float* x  = (const float*)d_in[0];
    const float* Wq = (const float*)d_in[1];
    const float* bq = (const float*)d_in[2];
    const float* Wk = (const float*)d_in[3];
    const float* bk = (const float*)d_in[4];
    const float* Wv = (const float*)d_in[5];
    const float* bv = (const float*)d_in[6];
    const float* Wo = (const float*)d_in[7];
    const float* bo = (const float*)d_in[8];
    float* out = (float*)d_out;

    // workspace (89,399,296 B total, same proven guard):
    //   [0,          67108864)  ek / eq  bf16 [b][c][n] (ek dead after t_mfma)
    //   [67108864,   83886080)  Tpart f32 [8][8][256][256] (chunk0 -> Tred in place)
    //   [83886080,   88080384)  invZ  f32 [8][16384][8]
    //       (early borrows: ctx f32 at +0 (524288 B); ksump f32 at +1048576
    //        (65536 B) — both dead before invz_pass writes)
    //   [88088576,   89137152)  Mb    bf16 [8][256][256]
    //   [89137152,   89268224)  Wqb   bf16
    //   [89268224,   89399296)  Wkb   bf16
    if (ws_size < (size_t)89399296) return;  // fail loud, not crash
    char* wsb = (char*)d_ws;
    unsigned short* ekq  = (unsigned short*)wsb;
    float*          Tpart= (float*)(wsb + 67108864);
    float*          invZ = (float*)(wsb + 83886080);
    float*          ctx  = (float*)(wsb + 83886080);            // borrow
    float*          ksump= (float*)(wsb + 83886080 + 1048576);  // borrow
    unsigned short* Mb   = (unsigned short*)(wsb + 88088576);
    unsigned short* Wqb  = (unsigned short*)(wsb + 89137152);
    unsigned short* Wkb  = (unsigned short*)(wsb + 89268224);

    prep      <<<256,             256, 0, stream>>>(Wq, Wk, Wqb, Wkb);
    proj_mfma <<<dim3(128, 2, 8), 256, 0, stream>>>(x, Wkb, bk, ekq);
    t_mfma    <<<dim3(4, 8, 8),   256, 0, stream>>>(ekq, x, Tpart, ksump);
    treduce   <<<512,             256, 0, stream>>>(Tpart, ksump);
    ctx_pass  <<<512,             256, 0, stream>>>(Tpart, Wv, bv, ctx);
    mpass     <<<2048,            256, 0, stream>>>(ctx, Wo, Mb);
    proj_mfma <<<dim3(128, 2, 8), 256, 0, stream>>>(x, Wqb, bq, ekq);
    invz_pass <<<dim3(64, 8),     256, 0, stream>>>(ekq, invZ);
    out_mfma  <<<dim3(128, 2, 8), 256, 0, stream>>>(ekq, invZ, Mb, bo, out);
}

// Round 7
// 324.815 us; speedup vs baseline: 1.0470x; 1.0470x over previous
//
#include <hip/hip_runtime.h>
#include <hip/hip_bf16.h>
#include <cstddef>

// ILA_10986526343542: linear attention block, bf16-MFMA pipeline.
// x:[8,256,128,128] fp32.
//   xTb = bf16(x)^T [b][n][c]                  (xt_pass, XT path only)
//   ek  = exp(s*(Wk@x+bk)) bf16 [b][c][n]      (proj_mfma<false>)
//   T   = ek @ x^T (8 n-chunks) + ksum partials (t_mfma)
//   Tred= (sum_chunks T)/ksum  (in-place)       (treduce)
//   ctx = Tred@Wv^T + bv                        (ctx_pass)
//   M   = Wo_h @ ctx_h^T  (bf16)                (mpass)
//   eqT = softmax_c-scaled exp(s*(Wq@x+bq)) bf16 [b][n][c]  (proj_mfma<true>,
//         per-head 1/Z applied in epilogue — invz_pass eliminated)
//   out = M @ eqT^T + bo                        (out_mfma)

constexpr int   NPIX     = 16384;
constexpr float QK_SCALE = 0.42044820762685725f;  // 32^-0.25

typedef __attribute__((ext_vector_type(8))) short          bf16x8;
typedef __attribute__((ext_vector_type(8))) unsigned short u16x8;
typedef __attribute__((ext_vector_type(4))) float          f32x4;

__device__ __forceinline__ float bf2f(unsigned short v) {
    union { unsigned int u; float f; } c; c.u = ((unsigned int)v) << 16; return c.f;
}
__device__ __forceinline__ unsigned short f2bf(float f) {
    union { __hip_bfloat16 h; unsigned short s; } c; c.h = __float2bfloat16(f); return c.s;
}
// async global->LDS, 16B per lane; dest = wave-uniform base + lane*16
__device__ __forceinline__ void gload_lds16(const void* g, void* l) {
    __builtin_amdgcn_global_load_lds(
        (const __attribute__((address_space(1))) unsigned int*)g,
        (__attribute__((address_space(3))) unsigned int*)l, 16, 0, 0);
}

// ---- 0: weights to bf16 ----------------------------------------------------
__global__ __launch_bounds__(256) void prep(
    const float* __restrict__ Wq, const float* __restrict__ Wk,
    unsigned short* __restrict__ Wqb, unsigned short* __restrict__ Wkb)
{
    const int i = blockIdx.x * 256 + threadIdx.x;   // 65536 total
    Wqb[i] = f2bf(Wq[i]);
    Wkb[i] = f2bf(Wk[i]);
}

// ---- 0b: xTb[b][n][c] = bf16(x) transposed (XT path) -----------------------
__global__ __launch_bounds__(256) void xt_pass(
    const float* __restrict__ x, unsigned short* __restrict__ xTb)
{
    __shared__ float tile[64][65];
    const int b = blockIdx.z, c0 = blockIdx.y * 64, n0 = blockIdx.x * 64;
    const int t = threadIdx.x;
    const int tr = t >> 2, tc = (t & 3) * 16;
    const float* src = x + ((size_t)b*256 + c0 + tr) * NPIX + n0 + tc;
    #pragma unroll
    for (int u = 0; u < 16; u += 4) {
        f32x4 v = *(const f32x4*)(src + u);
        tile[tr][tc+u+0] = v.x; tile[tr][tc+u+1] = v.y;
        tile[tr][tc+u+2] = v.z; tile[tr][tc+u+3] = v.w;
    }
    __syncthreads();
    unsigned short* dst = xTb + ((size_t)b*NPIX + n0 + tr) * 256 + c0 + tc;
    u16x8 p0, p1;
    #pragma unroll
    for (int u = 0; u < 8; ++u) p0[u] = f2bf(tile[tc+u][tr]);
    #pragma unroll
    for (int u = 0; u < 8; ++u) p1[u] = f2bf(tile[tc+8+u][tr]);
    *(u16x8*)dst = p0; *(u16x8*)(dst + 8) = p1;
}

// ---- 1/6: projection via MFMA ---------------------------------------------
// XT=true : A,B both via double-buffered global_load_lds from k-contiguous rows
//           (A=W rows, B=xTb rows). LDS rows are 64B; XOR-swizzle the 16B slot
//           on BOTH the global source and the fragment read (rule #21).
// XT=false: A via global_load_lds (swizzled), B via float2 gather -> BsT[128][40].
// Epilogue: Cs bounce; QPASS additionally folds per-head 1/Z (pre-scaled eqT).
typedef unsigned short lds_row32[32];
template<bool QPASS, bool XT>
__global__ __launch_bounds__(256) void proj_mfma(
    const float* __restrict__ x, const unsigned short* __restrict__ xTb,
    const unsigned short* __restrict__ Wb, const float* __restrict__ bias,
    unsigned short* __restrict__ eout)
{
    __shared__ alignas(16) unsigned char smem[36864];
    const int b  = blockIdx.z;
    const int m0 = blockIdx.y * 128;
    const int n0 = blockIdx.x * 128;
    const int t  = threadIdx.x;
    const int w  = t >> 6, l = t & 63;
    const int lm = l & 15, lg = l >> 4;
    const int mwl = (w & 1) * 64;
    const int nwl = (w >> 1) * 64;
    // swizzled fragment-read slot (shorts): lg XOR'd with s(lm)
    const int lgs = (lg ^ ((lm & 3) ^ ((lm >> 2) & 3))) * 8;
    // stage mapping for gload: lane covers row r16, swizzled 16B slot
    const int r16 = l >> 2;
    const int scb = (((l & 3) ^ ((r16 & 3) ^ ((r16 >> 2) & 3)))) * 8;

    const unsigned short* Abase = Wb + (size_t)m0 * 256;

    f32x4 acc[4][4] = {};

    if (XT) {
        lds_row32* As0 = (lds_row32*)smem;             // [2][128][32]
        lds_row32* Bs0 = (lds_row32*)(smem + 16384);
        const unsigned short* Bbase = xTb + ((size_t)b*NPIX + n0) * 256;
        auto stage = [&](int buf, int k0) {
            #pragma unroll
            for (int i = 0; i < 2; ++i) {
                const int row0 = w*32 + i*16;
                gload_lds16(Abase + (size_t)(row0 + r16)*256 + k0 + scb,
                            &As0[buf*128 + row0][0]);
                gload_lds16(Bbase + (size_t)(row0 + r16)*256 + k0 + scb,
                            &Bs0[buf*128 + row0][0]);
            }
        };
        stage(0, 0);
        __syncthreads();
        for (int t8 = 0; t8 < 8; ++t8) {
            const int cur = t8 & 1;
            if (t8 < 7) stage(cur ^ 1, (t8 + 1) * 32);
            bf16x8 afr[4], bfr[4];
            #pragma unroll
            for (int i = 0; i < 4; ++i)
                afr[i] = *(const bf16x8*)&As0[cur*128 + mwl + i*16 + lm][lgs];
            #pragma unroll
            for (int j = 0; j < 4; ++j)
                bfr[j] = *(const bf16x8*)&Bs0[cur*128 + nwl + j*16 + lm][lgs];
            #pragma unroll
            for (int i = 0; i < 4; ++i)
                #pragma unroll
                for (int j = 0; j < 4; ++j)
                    acc[i][j] = __builtin_amdgcn_mfma_f32_16x16x32_bf16(afr[i], bfr[j], acc[i][j], 0, 0, 0);
            __syncthreads();
        }
    } else {
        lds_row32* As1 = (lds_row32*)smem;                            // [128][32]
        unsigned short (*BsT)[40] = (unsigned short(*)[40])(smem + 16384);
        const float* xb = x + (size_t)b * 256 * NPIX + n0;
        const int np = (t & 63) * 2, kq = (t >> 6) * 8;
        for (int k0 = 0; k0 < 256; k0 += 32) {
            #pragma unroll
            for (int i = 0; i < 2; ++i) {
                const int row0 = w*32 + i*16;
                gload_lds16(Abase + (size_t)(row0 + r16)*256 + k0 + scb, &As1[row0][0]);
            }
            {   // B: x columns -> transposed LDS tile
                const float* src = xb + (size_t)(k0 + kq) * NPIX + np;
                float2 v[8];
                #pragma unroll
                for (int r = 0; r < 8; ++r)
                    v[r] = *(const float2*)(src + (size_t)r * NPIX);
                u16x8 pa, pb;
                #pragma unroll
                for (int r = 0; r < 8; ++r) { pa[r] = f2bf(v[r].x); pb[r] = f2bf(v[r].y); }
                *(u16x8*)&BsT[np][kq]     = pa;
                *(u16x8*)&BsT[np + 1][kq] = pb;
            }
            __syncthreads();
            bf16x8 afr[4], bfr[4];
            #pragma unroll
            for (int i = 0; i < 4; ++i)
                afr[i] = *(const bf16x8*)&As1[mwl + i*16 + lm][lgs];
            #pragma unroll
            for (int j = 0; j < 4; ++j)
                bfr[j] = *(const bf16x8*)&BsT[nwl + j*16 + lm][lg*8];
            #pragma unroll
            for (int i = 0; i < 4; ++i)
                #pragma unroll
                for (int j = 0; j < 4; ++j)
                    acc[i][j] = __builtin_amdgcn_mfma_f32_16x16x32_bf16(afr[i], bfr[j], acc[i][j], 0, 0, 0);
            __syncthreads();
        }
    }

    // epilogue: exp + bf16 via Cs bounce (aliases loop LDS; loop ended with barrier)
    unsigned short (*Cs)[64][72] = (unsigned short(*)[64][72])smem;
    const int mw = m0 + mwl, nw = n0 + nwl;
    #pragma unroll
    for (int i = 0; i < 4; ++i) {
        const f32x4 bb4 = *(const f32x4*)(bias + mw + i*16 + lg*4);
        #pragma unroll
        for (int r = 0; r < 4; ++r) {
            const int row = i*16 + lg*4 + r;
            #pragma unroll
            for (int j = 0; j < 4; ++j) {
                const int col = j*16 + lm;
                const unsigned short bs = f2bf(__expf(QK_SCALE * (acc[i][j][r] + bb4[r])));
                if (QPASS) Cs[w][col][row] = bs;   // [n-local][c-local]
                else       Cs[w][row][col] = bs;   // [c-local][n-local]
            }
        }
    }
    __syncthreads();

    if (QPASS) {
        // pixel l's 64 channels = 2 whole heads: fold 1/Z here (pre-scaled eqT)
        unsigned short* dst = eout + ((size_t)b * NPIX + nw + l) * 256 + mw;
        u16x8 vv[8];
        float z0 = 0.f, z1 = 0.f;
        #pragma unroll
        for (int s8 = 0; s8 < 8; ++s8) {
            vv[s8] = *(const u16x8*)&Cs[w][l][s8*8];
            float ps = 0.f;
            #pragma unroll
            for (int u = 0; u < 8; ++u) ps += bf2f(vv[s8][u]);
            if (s8 < 4) z0 += ps; else z1 += ps;
        }
        const float iz0 = 1.0f / z0, iz1 = 1.0f / z1;
        #pragma unroll
        for (int s8 = 0; s8 < 8; ++s8) {
            const float iz = (s8 < 4) ? iz0 : iz1;
            u16x8 o;
            #pragma unroll
            for (int u = 0; u < 8; ++u) o[u] = f2bf(bf2f(vv[s8][u]) * iz);
            *(u16x8*)(dst + s8*8) = o;
        }
    } else {
        unsigned short* dst = eout + ((size_t)b * 256 + mw + l) * NPIX + nw;
        #pragma unroll
        for (int s8 = 0; s8 < 8; ++s8)
            *(u16x8*)(dst + s8*8) = *(const u16x8*)&Cs[w][l][s8*8];
    }
}

// ---- 2: Tpart[b][chunk] = ek @ x^T via MFMA + ksum partials ----------------
__global__ __launch_bounds__(256) void t_mfma(
    const unsigned short* __restrict__ ek, const float* __restrict__ x,
    float* __restrict__ Tpart, float* __restrict__ ksump)
{
    __shared__ unsigned short As[128][40];
    __shared__ unsigned short Bs[128][40];
    const int quad  = blockIdx.x;
    const int chunk = blockIdx.y;
    const int b     = blockIdx.z;
    const int mt = (quad >> 1) * 128;
    const int ct = (quad & 1) * 128;
    const bool do_ks = (quad & 1) == 0;
    const int t  = threadIdx.x;
    const int w  = t >> 6, l = t & 63;
    const int lm = l & 15, lg = l >> 4;
    const int mw = (w & 1) * 64, cw = (w >> 1) * 64;
    const int sr = t >> 1, sh = (t & 1) * 16;

    const unsigned short* ekb = ek + ((size_t)b*256 + mt) * NPIX;
    const float*          xb  = x  + ((size_t)b*256 + ct) * NPIX;

    f32x4 acc[4][4] = {};
    float krow = 0.f;
    const int p0base = chunk * 2048;
    for (int p0 = p0base; p0 < p0base + 2048; p0 += 32) {
        {   // stage A: ek rows + row-sum accumulation
            const unsigned short* src = ekb + (size_t)sr * NPIX + p0 + sh;
            u16x8 a0 = *(const u16x8*)src;
            u16x8 a1 = *(const u16x8*)(src + 8);
            *(u16x8*)&As[sr][sh]     = a0;
            *(u16x8*)&As[sr][sh + 8] = a1;
            if (do_ks) {
                #pragma unroll
                for (int u = 0; u < 8; ++u) krow += bf2f(a0[u]) + bf2f(a1[u]);
            }
        }
        {   // stage B: x rows (fp32 -> bf16)
            const float* src = xb + (size_t)sr * NPIX + p0 + sh;
            u16x8 a, c;
            #pragma unroll
            for (int u = 0; u < 8; ++u) { a[u] = f2bf(src[u]); c[u] = f2bf(src[8+u]); }
            *(u16x8*)&Bs[sr][sh]     = a;
            *(u16x8*)&Bs[sr][sh + 8] = c;
        }
        __syncthreads();
        bf16x8 afr[4], bfr[4];
        #pragma unroll
        for (int i = 0; i < 4; ++i) afr[i] = *(const bf16x8*)&As[mw + i*16 + lm][lg*8];
        #pragma unroll
        for (int j = 0; j < 4; ++j) bfr[j] = *(const bf16x8*)&Bs[cw + j*16 + lm][lg*8];
        #pragma unroll
        for (int i = 0; i < 4; ++i)
            #pragma unroll
            for (int j = 0; j < 4; ++j)
                acc[i][j] = __builtin_amdgcn_mfma_f32_16x16x32_bf16(afr[i], bfr[j], acc[i][j], 0, 0, 0);
        __syncthreads();
    }

    if (do_ks) {
        krow += __shfl_xor(krow, 1, 64);
        if ((t & 1) == 0)
            ksump[((size_t)b*8 + chunk)*256 + mt + sr] = krow;
    }

    float* dst = Tpart + (((size_t)b*8 + chunk) * 256) * 256;
    #pragma unroll
    for (int i = 0; i < 4; ++i)
        #pragma unroll
        for (int r = 0; r < 4; ++r) {
            const int gm = mt + mw + i*16 + lg*4 + r;
            #pragma unroll
            for (int j = 0; j < 4; ++j)
                dst[(size_t)gm * 256 + ct + cw + j*16 + lm] = acc[i][j][r];
        }
}

// ---- 3a: reduce Tpart chunks in place, fold 1/ksum -------------------------
__global__ __launch_bounds__(256) void treduce(
    float* __restrict__ Tpart, const float* __restrict__ ksump)
{
    const int gid = blockIdx.x * 256 + threadIdx.x;
    const int b   = gid >> 14;
    const int rem = gid & 16383;
    const int r   = rem >> 6;
    const int c4  = (rem & 63) * 4;
    float ks = 0.f;
    #pragma unroll
    for (int ch = 0; ch < 8; ++ch) ks += ksump[((size_t)b*8 + ch)*256 + r];
    float* base = Tpart + (((size_t)b*8) * 256 + r) * 256 + c4;
    f32x4 s = *(f32x4*)base;
    #pragma unroll
    for (int ch = 1; ch < 8; ++ch) {
        f32x4 v = *(const f32x4*)(base + (size_t)ch * 65536);
        s.x += v.x; s.y += v.y; s.z += v.z; s.w += v.w;
    }
    const float inv = 1.0f / ks;
    s.x *= inv; s.y *= inv; s.z *= inv; s.w *= inv;
    *(f32x4*)base = s;
}

// ---- 3b: ctx = Tred@Wv^T + bv ---------------------------------------------
__global__ __launch_bounds__(256) void ctx_pass(
    const float* __restrict__ Tpart, const float* __restrict__ Wv,
    const float* __restrict__ bv, float* __restrict__ ctx)
{
    const int gid = blockIdx.x * 256 + threadIdx.x;
    const int b   = gid >> 14;
    const int rem = gid & 16383;
    const int h   = rem >> 11;
    const int de  = rem & 2047;
    const int d   = de >> 6;
    const int e   = de & 63;
    const float* tp = Tpart + (((size_t)b*8) * 256 + h*32 + d) * 256;
    const float* wv = Wv + (size_t)(h*64 + e) * 256;
    float sx = 0.f, sy = 0.f, sz = 0.f, sw = 0.f;
    #pragma unroll 8
    for (int c = 0; c < 256; c += 4) {
        f32x4 a = *(const f32x4*)(tp + c);
        f32x4 wv4 = *(const f32x4*)(wv + c);
        sx = fmaf(a.x, wv4.x, sx); sy = fmaf(a.y, wv4.y, sy);
        sz = fmaf(a.z, wv4.z, sz); sw = fmaf(a.w, wv4.w, sw);
    }
    ctx[gid] = (sx + sy) + (sz + sw) + bv[h*64 + e];
}

// ---- 3c: M = Wo_h @ ctx_h^T (bf16) -----------------------------------------
__global__ __launch_bounds__(256) void mpass(
    const float* __restrict__ ctx, const float* __restrict__ Wo,
    unsigned short* __restrict__ Mb)
{
    const int gid = blockIdx.x * 256 + threadIdx.x;
    const int b   = gid >> 16;
    const int rem = gid & 65535;
    const int o   = rem >> 8;
    const int dg  = rem & 255;
    const int h   = dg >> 5;
    const float* cp = ctx + ((size_t)b*8 + h) * 2048 + (dg & 31) * 64;
    const float* wp = Wo + (size_t)o * 512 + h*64;
    float sx = 0.f, sy = 0.f, sz = 0.f, sw = 0.f;
    #pragma unroll
    for (int e = 0; e < 64; e += 4) {
        f32x4 a = *(const f32x4*)(cp + e);
        f32x4 wv = *(const f32x4*)(wp + e);
        sx = fmaf(a.x, wv.x, sx); sy = fmaf(a.y, wv.y, sy);
        sz = fmaf(a.z, wv.z, sz); sw = fmaf(a.w, wv.w, sw);
    }
    Mb[((size_t)b*256 + o) * 256 + dg] = f2bf((sx + sy) + (sz + sw));
}

// ---- 4: out = M @ eqT^T + bo (dbuf global_load_lds, swizzled) --------------
__global__ __launch_bounds__(256) void out_mfma(
    const unsigned short* __restrict__ eqT, const unsigned short* __restrict__ Mb,
    const float* __restrict__ bo, float* __restrict__ out)
{
    __shared__ alignas(16) unsigned char smem[32768];
    lds_row32* As0 = (lds_row32*)smem;             // [2][128][32]
    lds_row32* Bs0 = (lds_row32*)(smem + 16384);
    const int b  = blockIdx.z;
    const int m0 = blockIdx.y * 128;
    const int n0 = blockIdx.x * 128;
    const int t  = threadIdx.x;
    const int w  = t >> 6, l = t & 63;
    const int lm = l & 15, lg = l >> 4;
    const int mwl = (w & 1) * 64, nwl = (w >> 1) * 64;
    const int lgs = (lg ^ ((lm & 3) ^ ((lm >> 2) & 3))) * 8;
    const int r16 = l >> 2;
    const int scb = (((l & 3) ^ ((r16 & 3) ^ ((r16 >> 2) & 3)))) * 8;

    const unsigned short* Abase = Mb  + ((size_t)b*256 + m0) * 256;
    const unsigned short* Bbase = eqT + ((size_t)b*NPIX + n0) * 256;

    auto stage = [&](int buf, int k0) {
        #pragma unroll
        for (int i = 0; i < 2; ++i) {
            const int row0 = w*32 + i*16;
            gload_lds16(Abase + (size_t)(row0 + r16)*256 + k0 + scb, &As0[buf*128 + row0][0]);
            gload_lds16(Bbase + (size_t)(row0 + r16)*256 + k0 + scb, &Bs0[buf*128 + row0][0]);
        }
    };

    f32x4 acc[4][4] = {};
    stage(0, 0);
    __syncthreads();
    for (int t8 = 0; t8 < 8; ++t8) {
        const int cur = t8 & 1;
        if (t8 < 7) stage(cur ^ 1, (t8 + 1) * 32);
        bf16x8 afr[4], bfr[4];
        #pragma unroll
        for (int i = 0; i < 4; ++i)
            afr[i] = *(const bf16x8*)&As0[cur*128 + mwl + i*16 + lm][lgs];
        #pragma unroll
        for (int j = 0; j < 4; ++j)
            bfr[j] = *(const bf16x8*)&Bs0[cur*128 + nwl + j*16 + lm][lgs];
        #pragma unroll
        for (int i = 0; i < 4; ++i)
            #pragma unroll
            for (int j = 0; j < 4; ++j)
                acc[i][j] = __builtin_amdgcn_mfma_f32_16x16x32_bf16(afr[i], bfr[j], acc[i][j], 0, 0, 0);
        __syncthreads();
    }

    #pragma unroll
    for (int i = 0; i < 4; ++i) {
        const f32x4 bb4 = *(const f32x4*)(bo + m0 + mwl + i*16 + lg*4);
        #pragma unroll
        for (int r = 0; r < 4; ++r) {
            const int gm = m0 + mwl + i*16 + lg*4 + r;
            float* dst = out + ((size_t)b*256 + gm) * NPIX + n0 + nwl;
            #pragma unroll
            for (int j = 0; j < 4; ++j)
                dst[j*16 + lm] = acc[i][j][r] + bb4[r];
        }
    }
}

// ---------------------------------------------------------------------------
extern "C" void kernel_launch(void* const* d_in, const int* in_sizes, int n_in,
                              void* d_out, int out_size, void* d_ws, size_t ws_size,
                              hipStream_t stream)
{
    const float* x  = (const float*)d_in[0];
    const float* Wq = (const float*)d_in[1];
    const float* bq = (const float*)d_in[2];
    const float* Wk = (const float*)d_in[3];
    const float* bk = (const float*)d_in[4];
    const float* Wv = (const float*)d_in[5];
    const float* bv = (const float*)d_in[6];
    const float* Wo = (const float*)d_in[7];
    const float* bo = (const float*)d_in[8];
    float* out = (float*)d_out;
    char* wsb = (char*)d_ws;

    // XT layout (152,901,632 B): ekq@0 (67MB) | xTb@67108864 (67MB) |
    //   Tpart@134217728 (16MB) | ksump@151001088 | Mb@151066624 |
    //   Wqb@152115200 | Wkb@152246272 | ctx@152377344
    // Fallback layout (89,399,296 B, proven): ekq@0 | Tpart@67108864 |
    //   ctx@83886080 | ksump@84934656 | Mb@88088576 | Wqb@89137152 | Wkb@89268224
    const bool use_xt = ws_size >= (size_t)152901632;
    if (!use_xt && ws_size < (size_t)89399296) return;  // fail loud, not crash

    unsigned short* ekq  = (unsigned short*)wsb;
    unsigned short* xTb;
    float *Tpart, *ksump, *ctx;
    unsigned short *Mb, *Wqb, *Wkb;
    if (use_xt) {
        xTb   = (unsigned short*)(wsb + 67108864);
        Tpart = (float*)(wsb + 134217728);
        ksump = (float*)(wsb + 151001088);
        Mb    = (unsigned short*)(wsb + 151066624);
        Wqb   = (unsigned short*)(wsb + 152115200);
        Wkb   = (unsigned short*)(wsb + 152246272);
        ctx   = (float*)(wsb + 152377344);
    } else {
        xTb   = nullptr;
        Tpart = (float*)(wsb + 67108864);
        ctx   = (float*)(wsb + 83886080);
        ksump = (float*)(wsb + 84934656);
        Mb    = (unsigned short*)(wsb + 88088576);
        Wqb   = (unsigned short*)(wsb + 89137152);
        Wkb   = (unsigned short*)(wsb + 89268224);
    }

    prep<<<256, 256, 0, stream>>>(Wq, Wk, Wqb, Wkb);
    if (use_xt) {
        xt_pass<<<dim3(256, 4, 8), 256, 0, stream>>>(x, xTb);
        proj_mfma<false, true><<<dim3(128, 2, 8), 256, 0, stream>>>(x, xTb, Wkb, bk, ekq);
    } else {
        proj_mfma<false, false><<<dim3(128, 2, 8), 256, 0, stream>>>(x, xTb, Wkb, bk, ekq);
    }
    t_mfma   <<<dim3(4, 8, 8), 256, 0, stream>>>(ekq, x, Tpart, ksump);
    treduce  <<<512,           256, 0, stream>>>(Tpart, ksump);
    ctx_pass <<<512,           256, 0, stream>>>(Tpart, Wv, bv, ctx);
    mpass    <<<2048,          256, 0, stream>>>(ctx, Wo, Mb);
    if (use_xt) {
        proj_mfma<true, true><<<dim3(128, 2, 8), 256, 0, stream>>>(x, xTb, Wqb, bq, ekq);
    } else {
        proj_mfma<true, false><<<dim3(128, 2, 8), 256, 0, stream>>>(x, xTb, Wqb, bq, ekq);
    }
    out_mfma<<<dim3(128, 2, 8), 256, 0, stream>>>(ekq, Mb, bo, out);
}